// Round 4
// baseline (985.226 us; speedup 1.0000x reference)
//
#include <hip/hip_runtime.h>

typedef unsigned short u16;
typedef __attribute__((ext_vector_type(8))) short bf16x8;  // 8 bf16 in 4 VGPRs
typedef __attribute__((ext_vector_type(4))) float f32x4;

constexpr int BATCH = 8192;
constexpr int UNITS = 1024;
constexpr int K2    = 2048;   // combined K  ([x | h_prev])
constexpr int N4    = 4096;   // 4*UNITS gate columns
constexpr int BK    = 32;     // K-tile (32 → 64 KB LDS → 2 blocks/CU)
constexpr int BM    = 256;    // batch rows per block
constexpr int BN    = 256;    // gate cols per block
constexpr int NKT   = K2 / BK;        // 64
constexpr int ASZ   = BM * BK;        // 8192 u16 = 16 KB per A buffer
constexpr int BSZ   = BN * BK;        // 8192 u16 = 16 KB per B buffer

__device__ __forceinline__ u16 f2bf(float f) {
  unsigned u = __float_as_uint(f);
  u += 0x7fffu + ((u >> 16) & 1u);   // round-to-nearest-even
  return (u16)(u >> 16);
}

__device__ __forceinline__ void async_copy16(const void* g, void* l) {
  __builtin_amdgcn_global_load_lds(
      (const __attribute__((address_space(1))) void*)g,
      (__attribute__((address_space(3))) void*)l, 16, 0, 0);
}

// ---------------------------------------------------------------------------
// Fused cast kernel (unchanged — BW-bound near roofline, conflict-free).
//   blocks [0, 2048):    B pack/transpose/permute  (64n x 64k tile per block)
//   blocks [2048, 6144): A = [x | h_prev] bf16 pack (grid-stride float4)
// B layout: bf16 [4096 p][2048 k], B[p][k] = src[k][oc(p)],
//   oc(p) = jn*1024 + (p>>6)*16 + (p&15), jn = (p>>4)&3  → any 64-aligned
//   group of B rows = the 4 gates of the same 16 units.
// ---------------------------------------------------------------------------
__global__ __launch_bounds__(256) void cast_fused_kernel(
    const float* __restrict__ x, const float* __restrict__ h,
    const float* __restrict__ W, const float* __restrict__ U,
    u16* __restrict__ A, u16* __restrict__ B) {
  const int tid = threadIdx.x;
  if (blockIdx.x < 2048) {
    __shared__ float lds[64 * 69];
    const int bid = blockIdx.x;
    const int nb  = bid & 63;
    const int kb  = bid >> 6;
    const int n0  = nb * 64;
    const int k0  = kb * 64;
    const int jn  = n0 >> 10;
    const int q0  = (n0 & 1023) >> 4;
    const float* src = (k0 < UNITS) ? (W + (size_t)k0 * N4)
                                    : (U + (size_t)(k0 - UNITS) * N4);
    {
      const int kk  = tid >> 4;
      const int nn4 = (tid & 15) * 4;
#pragma unroll
      for (int r = 0; r < 4; ++r) {
        const int k = kk + r * 16;
        float4 v = *reinterpret_cast<const float4*>(&src[(size_t)k * N4 + n0 + nn4]);
        lds[k * 69 + nn4 + 0] = v.x;
        lds[k * 69 + nn4 + 1] = v.y;
        lds[k * 69 + nn4 + 2] = v.z;
        lds[k * 69 + nn4 + 3] = v.w;
      }
    }
    __syncthreads();
    {
      const int kk4 = (tid & 15) * 4;
#pragma unroll
      for (int pass = 0; pass < 4; ++pass) {
        const int rr  = (tid >> 4) + pass * 16;
        const int q   = q0 + (rr >> 4);
        const int low = rr & 15;
        const int p   = q * 64 + jn * 16 + low;
        union { ushort4 u4; u16 s[4]; } o;
#pragma unroll
        for (int j = 0; j < 4; ++j) o.s[j] = f2bf(lds[(kk4 + j) * 69 + rr]);
        *reinterpret_cast<ushort4*>(&B[(size_t)p * K2 + k0 + kk4]) = o.u4;
      }
    }
  } else {
    const int t0 = (blockIdx.x - 2048) * 256 + tid;
    const int stride = 4096 * 256;
#pragma unroll
    for (int s = 0; s < 4; ++s) {
      const int g = t0 + s * stride;
      const int idx = g * 4;
      const int b = idx >> 11;
      const int k = idx & 2047;
      const float* src = (k < UNITS) ? (x + (size_t)b * UNITS + k)
                                     : (h + (size_t)b * UNITS + (k - UNITS));
      float4 v = *reinterpret_cast<const float4*>(src);
      union { ushort4 u4; u16 sv[4]; } o;
      o.sv[0] = f2bf(v.x); o.sv[1] = f2bf(v.y);
      o.sv[2] = f2bf(v.z); o.sv[3] = f2bf(v.w);
      *reinterpret_cast<ushort4*>(A + idx) = o.u4;
    }
  }
}

// ---------------------------------------------------------------------------
// 256x256 GEMM + fused peephole LSTM epilogue.  BK=32, double-buffered,
// LDS = 64 KB → TWO blocks per CU (R4 fix: 128/160 KB allowed only one, so
// every seam stalled the whole CU).  Independent co-resident blocks overlap
// each other's seam drains and ds_read latency with MFMAs.
// 8 waves (2M x 4N), per-wave 128x64 output, acc[8][4] (jn = gate).
// Per K-tile: {issue 4 global_load_lds for tile kt+1 | read 4 B-frags |
//   software-pipelined A-frag pairs ∥ 8-MFMA clusters (4 phases) |
//   seam: vmcnt(0) + s_barrier}.  No intra-tile barriers (reads hit stable
//   buffers; staging writes hit the other buffer).
// Swizzle: LDS row = 32 u16 = 4 slots of 16B; k-group g of row r stored at
// slot g^(r&3) via pre-swizzled GLOBAL source (lane fetches k-group
// (t&3)^((t>>2)&3)), LDS dest lane-linear; frag read slot = quad^(c&3)
// → uniform 8 lanes per 4-bank group = b128 service floor, no hot bank.
// ---------------------------------------------------------------------------
__global__ __launch_bounds__(512, 4) void lstm_gemm_kernel(
    const u16* __restrict__ A, const u16* __restrict__ B,
    const float* __restrict__ bias, const float* __restrict__ c_prev,
    const float* __restrict__ pf, const float* __restrict__ pi,
    const float* __restrict__ po,
    float* __restrict__ out_h, float* __restrict__ out_c) {
  __shared__ u16 lds[2 * ASZ + 2 * BSZ];   // 65536 B
  u16* const Asb = lds;            // 2 A buffers
  u16* const Bsb = lds + 2 * ASZ;  // 2 B buffers

  const int tid  = threadIdx.x;
  const int lane = tid & 63;
  const int wave = tid >> 6;
  const int quad = lane >> 4;
  const int c    = lane & 15;

  // XCD-aware bijective swizzle (nwg = 512, 512 % 8 == 0): each XCD gets
  // 64 consecutive tiles = 4 A-panels (4 MB, L2-resident) x all 16 B-panels.
  int lin = blockIdx.y * 16 + blockIdx.x;
  lin = (lin & 7) * 64 + (lin >> 3);
  const int m0 = (lin >> 4) * BM;
  const int n0 = (lin & 15) * BN;

  const int wm = (wave >> 2) * 128;   // 2 M-wave-groups
  const int wn = (wave & 3) * 64;     // 4 N-wave-groups

  // ---- staging: round i covers rows i*128 + (tid>>2), 4 lanes/row -------
  const int g8   = ((tid & 3) ^ ((tid >> 2) & 3)) * 8;  // pre-swizzled k-group
  const int rowa = tid >> 2;
  const u16* gA = A + (size_t)(m0 + rowa) * K2 + g8;
  const u16* gB = B + (size_t)(n0 + rowa) * K2 + g8;
  const int ldst = tid * 8;    // u16 idx: dest = buf_base + i*4096 + ldst

  // ---- fragment read offsets: row = base + c, slot = quad^(c&3) ---------
  const int slq  = (quad ^ (c & 3)) * 8;
  const int aoff = (wm + c) * BK + slq;   // + jm*512
  const int boff = (wn + c) * BK + slq;   // + jn*512

  f32x4 acc[8][4] = {};

  // ---- prologue: stage tile 0 into buf0 (4 loads), drain, barrier ----
#pragma unroll
  for (int i = 0; i < 2; ++i) {
    async_copy16(gA + (size_t)i * 128 * K2, &Asb[i * 4096 + ldst]);
    async_copy16(gB + (size_t)i * 128 * K2, &Bsb[i * 4096 + ldst]);
  }
  asm volatile("s_waitcnt vmcnt(0)" ::: "memory");
  __builtin_amdgcn_s_barrier();
  asm volatile("" ::: "memory");

#pragma unroll 2
  for (int kt = 0; kt < NKT; ++kt) {
    const u16* as = &Asb[(kt & 1) * ASZ];
    const u16* bs = &Bsb[(kt & 1) * BSZ];

    // -- issue staging for tile kt+1 into the other buffers (4 loads) --
    if (kt < NKT - 1) {
      u16* sA = &Asb[((kt + 1) & 1) * ASZ];
      u16* sB = &Bsb[((kt + 1) & 1) * BSZ];
      const size_t ok = (size_t)(kt + 1) * BK;
#pragma unroll
      for (int i = 0; i < 2; ++i) {
        async_copy16(gA + ok + (size_t)i * 128 * K2, sA + i * 4096 + ldst);
        async_copy16(gB + ok + (size_t)i * 128 * K2, sB + i * 4096 + ldst);
      }
    }

    // -- B fragments for the whole K-tile (4 ds_read_b128) --
    bf16x8 bfr[4];
#pragma unroll
    for (int jn = 0; jn < 4; ++jn)
      bfr[jn] = *(const bf16x8*)(bs + boff + jn * 512);

    // -- software-pipelined A-frag pairs ∥ 8-MFMA clusters --
    bf16x8 areg[2][2];   // [ph&1][jm01] — all indices compile-time
#pragma unroll
    for (int jm = 0; jm < 2; ++jm)
      areg[0][jm] = *(const bf16x8*)(as + aoff + jm * 512);

#pragma unroll
    for (int ph = 0; ph < 4; ++ph) {
      if (ph < 3) {
#pragma unroll
        for (int jm = 0; jm < 2; ++jm)
          areg[(ph + 1) & 1][jm] = *(const bf16x8*)(
              as + aoff + (2 * (ph + 1) + jm) * 512);
      }
      __builtin_amdgcn_s_setprio(1);
#pragma unroll
      for (int jm = 0; jm < 2; ++jm)
#pragma unroll
        for (int jn = 0; jn < 4; ++jn)
          acc[2 * ph + jm][jn] = __builtin_amdgcn_mfma_f32_16x16x32_bf16(
              areg[ph & 1][jm], bfr[jn], acc[2 * ph + jm][jn], 0, 0, 0);
      __builtin_amdgcn_s_setprio(0);
    }

    // -- seam: staged tile kt+1 landed everywhere; reads of kt consumed --
    if (kt < NKT - 1) {
      asm volatile("s_waitcnt vmcnt(0)" ::: "memory");
      __builtin_amdgcn_s_barrier();
      asm volatile("" ::: "memory");
    }
  }

  // ---- fused peephole-LSTM epilogue -------------------------------------
  const int u = ((n0 + wn) >> 2) + c;
  const float bf_ = bias[u];
  const float bi_ = bias[UNITS + u];
  const float bc_ = bias[2 * UNITS + u];
  const float bo_ = bias[3 * UNITS + u];
  const float pfv = pf[u], piv = pi[u], pov = po[u];
  const int mbase = m0 + wm + quad * 4;
#pragma unroll
  for (int jm = 0; jm < 8; ++jm) {
#pragma unroll
    for (int r = 0; r < 4; ++r) {
      const int b = mbase + jm * 16 + r;
      const float cp = c_prev[(size_t)b * UNITS + u];
      const float zf = acc[jm][0][r] + bf_ + pfv * cp;
      const float zi = acc[jm][1][r] + bi_ + piv * cp;
      const float zc = acc[jm][2][r] + bc_;
      const float zo = acc[jm][3][r] + bo_;
      const float fg = 1.f / (1.f + __expf(-zf));
      const float ig = 1.f / (1.f + __expf(-zi));
      const float ct = 1.f - 2.f / (__expf(2.f * zc) + 1.f);   // tanh, NaN-safe
      const float cn = fg * cp + ig * ct;
      const float og = 1.f / (1.f + __expf(-(zo + pov * cn)));
      const float hn = og * (1.f - 2.f / (__expf(2.f * cn) + 1.f));
      out_h[(size_t)b * UNITS + u] = hn;
      out_c[(size_t)b * UNITS + u] = cn;
    }
  }
}

// ---------------------------------------------------------------------------
extern "C" void kernel_launch(void* const* d_in, const int* in_sizes, int n_in,
                              void* d_out, int out_size, void* d_ws, size_t ws_size,
                              hipStream_t stream) {
  const float* x      = (const float*)d_in[0];   // [8192,1024]
  const float* c_prev = (const float*)d_in[1];   // [8192,1024]
  const float* h_prev = (const float*)d_in[2];   // [8192,1024]
  const float* W      = (const float*)d_in[3];   // [1024,4096]
  const float* U      = (const float*)d_in[4];   // [1024,4096]
  const float* bias   = (const float*)d_in[5];   // [4096]
  const float* pf     = (const float*)d_in[6];   // [1024]
  const float* pi     = (const float*)d_in[7];
  const float* po     = (const float*)d_in[8];
  float* out_h = (float*)d_out;
  float* out_c = out_h + (size_t)BATCH * UNITS;

  u16* Abf = (u16*)d_ws;                           // 32 MB
  u16* Bbf = Abf + (size_t)BATCH * K2;             // 16 MB

  cast_fused_kernel<<<6144, 256, 0, stream>>>(x, h_prev, W, U, Abf, Bbf);
  lstm_gemm_kernel<<<dim3(N4 / BN, BATCH / BM), 512, 0, stream>>>(
      Abf, Bbf, bias, c_prev, pf, pi, po, out_h, out_c);
}

// Round 6
// 200.210 us; speedup vs baseline: 4.9210x; 4.9210x over previous
//
#include <hip/hip_runtime.h>

typedef unsigned short u16;
typedef __attribute__((ext_vector_type(8))) short bf16x8;  // 8 bf16 in 4 VGPRs
typedef __attribute__((ext_vector_type(4))) float f32x4;

constexpr int BATCH = 8192;
constexpr int UNITS = 1024;
constexpr int K2    = 2048;   // combined K  ([x | h_prev])
constexpr int N4    = 4096;   // 4*UNITS gate columns
constexpr int BK    = 64;     // K-tile (128 B per row per tile — DO NOT shrink;
                              // BK=32's 64 B granularity caused 11x HBM over-fetch in R4)
constexpr int BM    = 256;    // batch rows per block
constexpr int BN    = 256;    // gate cols per block
constexpr int NKT   = K2 / BK;        // 32
constexpr int ASZ   = BM * BK;        // 16384 u16 = 32 KB per A buffer
constexpr int BSZ   = BN * BK;        // 16384 u16 = 32 KB per B buffer

__device__ __forceinline__ u16 f2bf(float f) {
  unsigned u = __float_as_uint(f);
  u += 0x7fffu + ((u >> 16) & 1u);   // round-to-nearest-even
  return (u16)(u >> 16);
}

__device__ __forceinline__ void async_copy16(const void* g, void* l) {
  __builtin_amdgcn_global_load_lds(
      (const __attribute__((address_space(1))) void*)g,
      (__attribute__((address_space(3))) void*)l, 16, 0, 0);
}

// ---------------------------------------------------------------------------
// Fused cast kernel (unchanged — BW-bound near roofline, conflict-free).
//   blocks [0, 2048):    B pack/transpose/permute  (64n x 64k tile per block)
//   blocks [2048, 6144): A = [x | h_prev] bf16 pack (grid-stride float4)
// B layout: bf16 [4096 p][2048 k], B[p][k] = src[k][oc(p)],
//   oc(p) = jn*1024 + (p>>6)*16 + (p&15), jn = (p>>4)&3  → any 64-aligned
//   group of B rows = the 4 gates of the same 16 units.
// ---------------------------------------------------------------------------
__global__ __launch_bounds__(256) void cast_fused_kernel(
    const float* __restrict__ x, const float* __restrict__ h,
    const float* __restrict__ W, const float* __restrict__ U,
    u16* __restrict__ A, u16* __restrict__ B) {
  const int tid = threadIdx.x;
  if (blockIdx.x < 2048) {
    __shared__ float lds[64 * 69];
    const int bid = blockIdx.x;
    const int nb  = bid & 63;
    const int kb  = bid >> 6;
    const int n0  = nb * 64;
    const int k0  = kb * 64;
    const int jn  = n0 >> 10;
    const int q0  = (n0 & 1023) >> 4;
    const float* src = (k0 < UNITS) ? (W + (size_t)k0 * N4)
                                    : (U + (size_t)(k0 - UNITS) * N4);
    {
      const int kk  = tid >> 4;
      const int nn4 = (tid & 15) * 4;
#pragma unroll
      for (int r = 0; r < 4; ++r) {
        const int k = kk + r * 16;
        float4 v = *reinterpret_cast<const float4*>(&src[(size_t)k * N4 + n0 + nn4]);
        lds[k * 69 + nn4 + 0] = v.x;
        lds[k * 69 + nn4 + 1] = v.y;
        lds[k * 69 + nn4 + 2] = v.z;
        lds[k * 69 + nn4 + 3] = v.w;
      }
    }
    __syncthreads();
    {
      const int kk4 = (tid & 15) * 4;
#pragma unroll
      for (int pass = 0; pass < 4; ++pass) {
        const int rr  = (tid >> 4) + pass * 16;
        const int q   = q0 + (rr >> 4);
        const int low = rr & 15;
        const int p   = q * 64 + jn * 16 + low;
        union { ushort4 u4; u16 s[4]; } o;
#pragma unroll
        for (int j = 0; j < 4; ++j) o.s[j] = f2bf(lds[(kk4 + j) * 69 + rr]);
        *reinterpret_cast<ushort4*>(&B[(size_t)p * K2 + k0 + kk4]) = o.u4;
      }
    }
  } else {
    const int t0 = (blockIdx.x - 2048) * 256 + tid;
    const int stride = 4096 * 256;
#pragma unroll
    for (int s = 0; s < 4; ++s) {
      const int g = t0 + s * stride;
      const int idx = g * 4;
      const int b = idx >> 11;
      const int k = idx & 2047;
      const float* src = (k < UNITS) ? (x + (size_t)b * UNITS + k)
                                     : (h + (size_t)b * UNITS + (k - UNITS));
      float4 v = *reinterpret_cast<const float4*>(src);
      union { ushort4 u4; u16 sv[4]; } o;
      o.sv[0] = f2bf(v.x); o.sv[1] = f2bf(v.y);
      o.sv[2] = f2bf(v.z); o.sv[3] = f2bf(v.w);
      *reinterpret_cast<ushort4*>(A + idx) = o.u4;
    }
  }
}

// ---------------------------------------------------------------------------
// 256x256 GEMM + fused peephole LSTM epilogue.  BK=64, double-buffered
// (128 KB LDS, 1 block/CU), 8 waves (2M x 4N), per-wave 128x64, acc[8][4].
// PERSISTENT: grid = 256 (1/CU); each block does two output tiles (m, n)
// and (m, n+8 panels) — same A-panel (L2-warm), same XCD mapping as R3.
// Rep-1's tile-0 staging is issued during rep-0's last tile and the rep-0
// epilogue runs BEFORE the drain, hiding epilogue VALU and prologue-2.
// Per K-tile, 4 phases (ks-major): p0=ks0*jm0-3, p1=ks0*jm4-7,
// p2=ks1*jm0-3, p3=ks1*jm4-7.  Stage-issues split 4+4 at p0/p1 (last issue
// >=2 phases before the seam's vmcnt(0) → no drain stall); frag ds_reads
// spread 4-8/phase, each one phase ahead of use (R5 fix: R3 front-loaded
// all 8 issues + 12 reads at the tile head → per-seam convoy).
// No intra-tile barriers; one vmcnt(0)+s_barrier seam per K-tile.
// Swizzle (0-conflict, verified): LDS row = 64 u16 = 8 slots of 16B;
// k-group g of row r at slot g^(r&7) via pre-swizzled GLOBAL source, LDS
// dest lane-linear; frag read slot = (ks*4+quad)^(c&7).
// ---------------------------------------------------------------------------
__global__ __launch_bounds__(512, 2) void lstm_gemm_kernel(
    const u16* __restrict__ A, const u16* __restrict__ B,
    const float* __restrict__ bias, const float* __restrict__ c_prev,
    const float* __restrict__ pf, const float* __restrict__ pi,
    const float* __restrict__ po,
    float* __restrict__ out_h, float* __restrict__ out_c) {
  __shared__ u16 lds[2 * ASZ + 2 * BSZ];   // 131072 B
  u16* const Asb = lds;            // 2 A buffers
  u16* const Bsb = lds + 2 * ASZ;  // 2 B buffers

  const int tid  = threadIdx.x;
  const int lane = tid & 63;
  const int wave = tid >> 6;
  const int quad = lane >> 4;
  const int c    = lane & 15;

  // Persistent pairing: block b -> orig {o, o+64}; XCD swizzle on orig.
  // lin = (orig&7)*64 + orig>>3; pair shares m-panel, n-panels differ by 8.
  const int b    = blockIdx.x;
  const int orig = (b >> 6) * 128 + (b & 63);
  const int lin  = (orig & 7) * 64 + (orig >> 3);
  const int m0   = (lin >> 4) * BM;
  const int n0a  = (lin & 15) * BN;          // in [0, 2048)

  const int wm = (wave >> 2) * 128;   // 2 M-wave-groups
  const int wn = (wave & 3) * 64;     // 4 N-wave-groups

  // ---- staging: round i covers rows i*64 + (tid>>3), 8 lanes/row --------
  const int g8   = ((tid & 7) ^ ((tid >> 3) & 7)) * 8;  // pre-swizzled k-group
  const int rowa = tid >> 3;
  const u16* gA  = A + (size_t)(m0 + rowa) * K2 + g8;
  const u16* gB0 = B + (size_t)(n0a + rowa) * K2 + g8;
  const u16* gB1 = gB0 + (size_t)2048 * K2;            // n-panel +8
  const int ldst = tid * 8;    // u16 idx: dest = buf_base + i*4096 + ldst

  // ---- fragment read offsets (slot = (ks*4+quad)^(c&7), row&7 == c&7) ---
  const int sl0   = (quad ^ (c & 7)) * 8;
  const int sl1   = ((4 + quad) ^ (c & 7)) * 8;
  const int aoff0 = (wm + c) * 64 + sl0;   // + jm*1024
  const int aoff1 = (wm + c) * 64 + sl1;
  const int boff0 = (wn + c) * 64 + sl0;   // + jn*1024
  const int boff1 = (wn + c) * 64 + sl1;

  f32x4 acc[8][4];

  // ---- prologue: stage rep-0 tile 0 into buf0 (8 loads), drain, barrier --
#pragma unroll
  for (int i = 0; i < 4; ++i) {
    async_copy16(gA + (size_t)i * 64 * K2, &Asb[i * 4096 + ldst]);
    async_copy16(gB0 + (size_t)i * 64 * K2, &Bsb[i * 4096 + ldst]);
  }
  asm volatile("s_waitcnt vmcnt(0)" ::: "memory");
  __builtin_amdgcn_s_barrier();

#pragma unroll 1
  for (int rep = 0; rep < 2; ++rep) {
    const u16* gBr = rep ? gB1 : gB0;
#pragma unroll
    for (int jm = 0; jm < 8; ++jm)
#pragma unroll
      for (int jn = 0; jn < 4; ++jn)
        acc[jm][jn] = (f32x4){0.f, 0.f, 0.f, 0.f};

#pragma unroll 2
    for (int kt = 0; kt < NKT; ++kt) {
      const u16* as = &Asb[(kt & 1) * ASZ];
      const u16* bs = &Bsb[(kt & 1) * BSZ];
      u16* sA = &Asb[((kt + 1) & 1) * ASZ];
      u16* sB = &Bsb[((kt + 1) & 1) * BSZ];
      const bool last  = (kt == NKT - 1);
      const bool stage = !last || (rep == 0);
      // next-tile sources; at rep-0's last tile, stage rep-1's tile 0.
      const u16* nA = !last ? gA  + (size_t)(kt + 1) * BK : gA;
      const u16* nB = !last ? gBr + (size_t)(kt + 1) * BK : gB1;

      // head: B(ks0) + A(ks0, jm0-3)  [8 ds_read_b128]
      bf16x8 bq0[4], aq[4];
#pragma unroll
      for (int jn = 0; jn < 4; ++jn)
        bq0[jn] = *(const bf16x8*)(bs + boff0 + jn * 1024);
#pragma unroll
      for (int jm = 0; jm < 4; ++jm)
        aq[jm] = *(const bf16x8*)(as + aoff0 + jm * 1024);

      // ---- p0: issue 4 stage loads | read A(ks0, jm4-7) | MFMA ks0 lo ----
      if (stage) {
        async_copy16(nA,                      sA + ldst);
        async_copy16(nA + (size_t)64 * K2,    sA + 4096 + ldst);
        async_copy16(nB,                      sB + ldst);
        async_copy16(nB + (size_t)64 * K2,    sB + 4096 + ldst);
      }
      bf16x8 ar[4];
#pragma unroll
      for (int jm = 0; jm < 4; ++jm)
        ar[jm] = *(const bf16x8*)(as + aoff0 + (4 + jm) * 1024);
      __builtin_amdgcn_s_setprio(1);
#pragma unroll
      for (int jm = 0; jm < 4; ++jm)
#pragma unroll
        for (int jn = 0; jn < 4; ++jn)
          acc[jm][jn] = __builtin_amdgcn_mfma_f32_16x16x32_bf16(
              aq[jm], bq0[jn], acc[jm][jn], 0, 0, 0);
      __builtin_amdgcn_s_setprio(0);

      // ---- p1: issue 4 stage loads | read B(ks1) + A(ks1, jm0-3) | ks0 hi
      if (stage) {
        async_copy16(nA + (size_t)128 * K2,   sA + 8192 + ldst);
        async_copy16(nA + (size_t)192 * K2,   sA + 12288 + ldst);
        async_copy16(nB + (size_t)128 * K2,   sB + 8192 + ldst);
        async_copy16(nB + (size_t)192 * K2,   sB + 12288 + ldst);
      }
      bf16x8 bq1[4], ac2[4];
#pragma unroll
      for (int jn = 0; jn < 4; ++jn)
        bq1[jn] = *(const bf16x8*)(bs + boff1 + jn * 1024);
#pragma unroll
      for (int jm = 0; jm < 4; ++jm)
        ac2[jm] = *(const bf16x8*)(as + aoff1 + jm * 1024);
      __builtin_amdgcn_s_setprio(1);
#pragma unroll
      for (int jm = 0; jm < 4; ++jm)
#pragma unroll
        for (int jn = 0; jn < 4; ++jn)
          acc[4 + jm][jn] = __builtin_amdgcn_mfma_f32_16x16x32_bf16(
              ar[jm], bq0[jn], acc[4 + jm][jn], 0, 0, 0);
      __builtin_amdgcn_s_setprio(0);

      // ---- p2: read A(ks1, jm4-7) | MFMA ks1 lo --------------------------
      bf16x8 ad[4];
#pragma unroll
      for (int jm = 0; jm < 4; ++jm)
        ad[jm] = *(const bf16x8*)(as + aoff1 + (4 + jm) * 1024);
      __builtin_amdgcn_s_setprio(1);
#pragma unroll
      for (int jm = 0; jm < 4; ++jm)
#pragma unroll
        for (int jn = 0; jn < 4; ++jn)
          acc[jm][jn] = __builtin_amdgcn_mfma_f32_16x16x32_bf16(
              ac2[jm], bq1[jn], acc[jm][jn], 0, 0, 0);
      __builtin_amdgcn_s_setprio(0);

      // ---- p3: MFMA ks1 hi ----------------------------------------------
      __builtin_amdgcn_s_setprio(1);
#pragma unroll
      for (int jm = 0; jm < 4; ++jm)
#pragma unroll
        for (int jn = 0; jn < 4; ++jn)
          acc[4 + jm][jn] = __builtin_amdgcn_mfma_f32_16x16x32_bf16(
              ad[jm], bq1[jn], acc[4 + jm][jn], 0, 0, 0);
      __builtin_amdgcn_s_setprio(0);

      // ---- seam: staged tile landed everywhere; reads of kt consumed ----
      if (!last) {
        asm volatile("s_waitcnt vmcnt(0)" ::: "memory");
        __builtin_amdgcn_s_barrier();
      }
    }

    // ---- fused peephole-LSTM epilogue (runs BEFORE rep-1's drain) -------
    {
      const int n0 = n0a + rep * 2048;
      const int u = ((n0 + wn) >> 2) + c;
      const float bf_ = bias[u];
      const float bi_ = bias[UNITS + u];
      const float bc_ = bias[2 * UNITS + u];
      const float bo_ = bias[3 * UNITS + u];
      const float pfv = pf[u], piv = pi[u], pov = po[u];
      const int mbase = m0 + wm + quad * 4;
#pragma unroll
      for (int jm = 0; jm < 8; ++jm) {
#pragma unroll
        for (int r = 0; r < 4; ++r) {
          const int bb = mbase + jm * 16 + r;
          const float cp = c_prev[(size_t)bb * UNITS + u];
          const float zf = acc[jm][0][r] + bf_ + pfv * cp;
          const float zi = acc[jm][1][r] + bi_ + piv * cp;
          const float zc = acc[jm][2][r] + bc_;
          const float zo = acc[jm][3][r] + bo_;
          const float fg = 1.f / (1.f + __expf(-zf));
          const float ig = 1.f / (1.f + __expf(-zi));
          const float ct = 1.f - 2.f / (__expf(2.f * zc) + 1.f);   // tanh
          const float cn = fg * cp + ig * ct;
          const float og = 1.f / (1.f + __expf(-(zo + pov * cn)));
          const float hn = og * (1.f - 2.f / (__expf(2.f * cn) + 1.f));
          out_h[(size_t)bb * UNITS + u] = hn;
          out_c[(size_t)bb * UNITS + u] = cn;
        }
      }
    }
    if (rep == 0) {   // rep-1 tile-0 staging (issued at last tile) now drains
      asm volatile("s_waitcnt vmcnt(0)" ::: "memory");
      __builtin_amdgcn_s_barrier();
    }
  }
}

// ---------------------------------------------------------------------------
extern "C" void kernel_launch(void* const* d_in, const int* in_sizes, int n_in,
                              void* d_out, int out_size, void* d_ws, size_t ws_size,
                              hipStream_t stream) {
  const float* x      = (const float*)d_in[0];   // [8192,1024]
  const float* c_prev = (const float*)d_in[1];   // [8192,1024]
  const float* h_prev = (const float*)d_in[2];   // [8192,1024]
  const float* W      = (const float*)d_in[3];   // [1024,4096]
  const float* U      = (const float*)d_in[4];   // [1024,4096]
  const float* bias   = (const float*)d_in[5];   // [4096]
  const float* pf     = (const float*)d_in[6];   // [1024]
  const float* pi     = (const float*)d_in[7];
  const float* po     = (const float*)d_in[8];
  float* out_h = (float*)d_out;
  float* out_c = out_h + (size_t)BATCH * UNITS;

  u16* Abf = (u16*)d_ws;                           // 32 MB
  u16* Bbf = Abf + (size_t)BATCH * K2;             // 16 MB

  cast_fused_kernel<<<6144, 256, 0, stream>>>(x, h_prev, W, U, Abf, Bbf);
  lstm_gemm_kernel<<<256, 512, 0, stream>>>(
      Abf, Bbf, bias, c_prev, pf, pi, po, out_h, out_c);
}

// Round 7
// 170.456 us; speedup vs baseline: 5.7799x; 1.1746x over previous
//
#include <hip/hip_runtime.h>

typedef unsigned short u16;
typedef __attribute__((ext_vector_type(8))) short bf16x8;  // 8 bf16 in 4 VGPRs
typedef __attribute__((ext_vector_type(4))) float f32x4;

constexpr int BATCH = 8192;
constexpr int UNITS = 1024;
constexpr int K2    = 2048;   // combined K  ([x | h_prev])
constexpr int N4    = 4096;   // 4*UNITS gate columns
constexpr int BK    = 64;     // K-tile (128 B per row per tile — DO NOT shrink;
                              // BK=32's 64 B granularity caused 11x HBM over-fetch in R4)
constexpr int BM    = 128;    // batch rows per block   (R7: 128x128 tile)
constexpr int BN    = 128;    // gate cols per block
constexpr int NKT   = K2 / BK;        // 32
constexpr int ASZ   = BM * BK;        // 8192 u16 = 16 KB per A buffer
constexpr int BSZ   = BN * BK;        // 8192 u16 = 16 KB per B buffer

__device__ __forceinline__ u16 f2bf(float f) {
  unsigned u = __float_as_uint(f);
  u += 0x7fffu + ((u >> 16) & 1u);   // round-to-nearest-even
  return (u16)(u >> 16);
}

__device__ __forceinline__ void async_copy16(const void* g, void* l) {
  __builtin_amdgcn_global_load_lds(
      (const __attribute__((address_space(1))) void*)g,
      (__attribute__((address_space(3))) void*)l, 16, 0, 0);
}

// ---------------------------------------------------------------------------
// Fused cast kernel (unchanged — BW-bound near roofline, conflict-free).
//   blocks [0, 2048):    B pack/transpose/permute  (64n x 64k tile per block)
//   blocks [2048, 6144): A = [x | h_prev] bf16 pack (grid-stride float4)
// B layout: bf16 [4096 p][2048 k], B[p][k] = src[k][oc(p)],
//   oc(p) = jn*1024 + (p>>6)*16 + (p&15), jn = (p>>4)&3  → any 64-aligned
//   group of B rows = the 4 gates of the same 16 units.
// ---------------------------------------------------------------------------
__global__ __launch_bounds__(256) void cast_fused_kernel(
    const float* __restrict__ x, const float* __restrict__ h,
    const float* __restrict__ W, const float* __restrict__ U,
    u16* __restrict__ A, u16* __restrict__ B) {
  const int tid = threadIdx.x;
  if (blockIdx.x < 2048) {
    __shared__ float lds[64 * 69];
    const int bid = blockIdx.x;
    const int nb  = bid & 63;
    const int kb  = bid >> 6;
    const int n0  = nb * 64;
    const int k0  = kb * 64;
    const int jn  = n0 >> 10;
    const int q0  = (n0 & 1023) >> 4;
    const float* src = (k0 < UNITS) ? (W + (size_t)k0 * N4)
                                    : (U + (size_t)(k0 - UNITS) * N4);
    {
      const int kk  = tid >> 4;
      const int nn4 = (tid & 15) * 4;
#pragma unroll
      for (int r = 0; r < 4; ++r) {
        const int k = kk + r * 16;
        float4 v = *reinterpret_cast<const float4*>(&src[(size_t)k * N4 + n0 + nn4]);
        lds[k * 69 + nn4 + 0] = v.x;
        lds[k * 69 + nn4 + 1] = v.y;
        lds[k * 69 + nn4 + 2] = v.z;
        lds[k * 69 + nn4 + 3] = v.w;
      }
    }
    __syncthreads();
    {
      const int kk4 = (tid & 15) * 4;
#pragma unroll
      for (int pass = 0; pass < 4; ++pass) {
        const int rr  = (tid >> 4) + pass * 16;
        const int q   = q0 + (rr >> 4);
        const int low = rr & 15;
        const int p   = q * 64 + jn * 16 + low;
        union { ushort4 u4; u16 s[4]; } o;
#pragma unroll
        for (int j = 0; j < 4; ++j) o.s[j] = f2bf(lds[(kk4 + j) * 69 + rr]);
        *reinterpret_cast<ushort4*>(&B[(size_t)p * K2 + k0 + kk4]) = o.u4;
      }
    }
  } else {
    const int t0 = (blockIdx.x - 2048) * 256 + tid;
    const int stride = 4096 * 256;
#pragma unroll
    for (int s = 0; s < 4; ++s) {
      const int g = t0 + s * stride;
      const int idx = g * 4;
      const int b = idx >> 11;
      const int k = idx & 2047;
      const float* src = (k < UNITS) ? (x + (size_t)b * UNITS + k)
                                     : (h + (size_t)b * UNITS + (k - UNITS));
      float4 v = *reinterpret_cast<const float4*>(src);
      union { ushort4 u4; u16 sv[4]; } o;
      o.sv[0] = f2bf(v.x); o.sv[1] = f2bf(v.y);
      o.sv[2] = f2bf(v.z); o.sv[3] = f2bf(v.w);
      *reinterpret_cast<ushort4*>(A + idx) = o.u4;
    }
  }
}

// ---------------------------------------------------------------------------
// 128x128 GEMM + fused peephole LSTM epilogue.  BK=64, double-buffered,
// LDS = 64 KB → TWO blocks per CU (R7: the R4 occupancy goal WITHOUT the
// BK=32 fetch-granularity trap — every staged row is a full 128 B line;
// L3 (256 MB) holds A+B (48 MB) so cross-block re-reads don't hit HBM).
// Independent co-resident blocks overlap each other's seam drains and
// post-barrier LDS refills with MFMA — the overlap 1-block/CU can't have.
// 8 waves (4M x 2N), per-wave 32x64 output, acc[2][4] (jn = gate; each
// wave spans all 4 gates of its 16 units → fused epilogue unchanged).
// Per K-tile: {issue 4 gload_lds for kt+1 | read ks0 frags (6 ds) |
//   MFMA ks0 (8) ∥ read ks1 frags (6 ds) | MFMA ks1 (8) |
//   seam: vmcnt(0) + s_barrier}.  Loads issued a full tile before drain.
// Swizzle (0-conflict, verified): LDS row = 64 u16 = 8 slots of 16B;
// k-group g of row r at slot g^(r&7) via pre-swizzled GLOBAL source, LDS
// dest lane-linear; frag read slot = (ks*4+quad)^(c&7).
// ---------------------------------------------------------------------------
__global__ __launch_bounds__(512, 4) void lstm_gemm_kernel(
    const u16* __restrict__ A, const u16* __restrict__ B,
    const float* __restrict__ bias, const float* __restrict__ c_prev,
    const float* __restrict__ pf, const float* __restrict__ pi,
    const float* __restrict__ po,
    float* __restrict__ out_h, float* __restrict__ out_c) {
  __shared__ u16 lds[2 * ASZ + 2 * BSZ];   // 65536 B → 2 blocks/CU
  u16* const Asb = lds;            // 2 A buffers
  u16* const Bsb = lds + 2 * ASZ;  // 2 B buffers

  const int tid  = threadIdx.x;
  const int lane = tid & 63;
  const int wave = tid >> 6;
  const int quad = lane >> 4;
  const int c    = lane & 15;

  // XCD-aware bijective swizzle (nwg = 2048, 2048 % 8 == 0): each XCD gets
  // 256 consecutive tiles = 8 A-panels (4 MB, L2-resident) x all 32 B-panels.
  const int lin = blockIdx.x;
  const int swz = (lin & 7) * 256 + (lin >> 3);
  const int m0  = (swz >> 5) * BM;   // 64 m-tiles
  const int n0  = (swz & 31) * BN;   // 32 n-tiles

  const int wm = (wave >> 1) * 32;   // 4 M-wave-groups
  const int wn = (wave & 1) * 64;    // 2 N-wave-groups (jn spans 4 gates)

  // ---- staging: round i covers rows i*64 + (tid>>3), 8 lanes/row --------
  const int g8   = ((tid & 7) ^ ((tid >> 3) & 7)) * 8;  // pre-swizzled k-group
  const int rowa = tid >> 3;
  const u16* gA = A + (size_t)(m0 + rowa) * K2 + g8;
  const u16* gB = B + (size_t)(n0 + rowa) * K2 + g8;
  const int ldst = tid * 8;    // u16 idx: dest = buf_base + i*4096 + ldst

  // ---- fragment read offsets (slot = (ks*4+quad)^(c&7), row&7 == c&7) ---
  const int sl0   = (quad ^ (c & 7)) * 8;
  const int sl1   = ((4 + quad) ^ (c & 7)) * 8;
  const int aoff0 = (wm + c) * 64 + sl0;   // + jm*1024
  const int aoff1 = (wm + c) * 64 + sl1;
  const int boff0 = (wn + c) * 64 + sl0;   // + jn*1024
  const int boff1 = (wn + c) * 64 + sl1;

  f32x4 acc[2][4] = {};

  // ---- prologue: stage tile 0 into buf0 (4 loads), drain, barrier ----
#pragma unroll
  for (int i = 0; i < 2; ++i) {
    async_copy16(gA + (size_t)i * 64 * K2, &Asb[i * 4096 + ldst]);
    async_copy16(gB + (size_t)i * 64 * K2, &Bsb[i * 4096 + ldst]);
  }
  asm volatile("s_waitcnt vmcnt(0)" ::: "memory");
  __builtin_amdgcn_s_barrier();

#pragma unroll 2
  for (int kt = 0; kt < NKT; ++kt) {
    const u16* as = &Asb[(kt & 1) * ASZ];
    const u16* bs = &Bsb[(kt & 1) * BSZ];

    // -- issue staging for tile kt+1 into the other buffers (4 loads) --
    if (kt < NKT - 1) {
      u16* sA = &Asb[((kt + 1) & 1) * ASZ];
      u16* sB = &Bsb[((kt + 1) & 1) * BSZ];
      const size_t ok = (size_t)(kt + 1) * BK;
#pragma unroll
      for (int i = 0; i < 2; ++i) {
        async_copy16(gA + ok + (size_t)i * 64 * K2, sA + i * 4096 + ldst);
        async_copy16(gB + ok + (size_t)i * 64 * K2, sB + i * 4096 + ldst);
      }
    }

    // -- ks0 fragments: B jn0-3 (4 ds) + A jm0-1 (2 ds) --
    bf16x8 bq0[4], aq0[2];
#pragma unroll
    for (int jn = 0; jn < 4; ++jn)
      bq0[jn] = *(const bf16x8*)(bs + boff0 + jn * 1024);
#pragma unroll
    for (int jm = 0; jm < 2; ++jm)
      aq0[jm] = *(const bf16x8*)(as + aoff0 + jm * 1024);

    // -- ks1 fragment reads (compiler interleaves with ks0 MFMA below) --
    bf16x8 bq1[4], aq1[2];
#pragma unroll
    for (int jn = 0; jn < 4; ++jn)
      bq1[jn] = *(const bf16x8*)(bs + boff1 + jn * 1024);
#pragma unroll
    for (int jm = 0; jm < 2; ++jm)
      aq1[jm] = *(const bf16x8*)(as + aoff1 + jm * 1024);

    // -- MFMA ks0 (8) --
    __builtin_amdgcn_s_setprio(1);
#pragma unroll
    for (int jm = 0; jm < 2; ++jm)
#pragma unroll
      for (int jn = 0; jn < 4; ++jn)
        acc[jm][jn] = __builtin_amdgcn_mfma_f32_16x16x32_bf16(
            aq0[jm], bq0[jn], acc[jm][jn], 0, 0, 0);
    __builtin_amdgcn_s_setprio(0);

    // -- MFMA ks1 (8) --
    __builtin_amdgcn_s_setprio(1);
#pragma unroll
    for (int jm = 0; jm < 2; ++jm)
#pragma unroll
      for (int jn = 0; jn < 4; ++jn)
        acc[jm][jn] = __builtin_amdgcn_mfma_f32_16x16x32_bf16(
            aq1[jm], bq1[jn], acc[jm][jn], 0, 0, 0);
    __builtin_amdgcn_s_setprio(0);

    // -- seam: staged tile kt+1 landed everywhere; reads of kt consumed --
    if (kt < NKT - 1) {
      asm volatile("s_waitcnt vmcnt(0)" ::: "memory");
      __builtin_amdgcn_s_barrier();
    }
  }

  // ---- fused peephole-LSTM epilogue -------------------------------------
  const int u = ((n0 + wn) >> 2) + c;
  const float bf_ = bias[u];
  const float bi_ = bias[UNITS + u];
  const float bc_ = bias[2 * UNITS + u];
  const float bo_ = bias[3 * UNITS + u];
  const float pfv = pf[u], piv = pi[u], pov = po[u];
  const int mbase = m0 + wm + quad * 4;
#pragma unroll
  for (int jm = 0; jm < 2; ++jm) {
#pragma unroll
    for (int r = 0; r < 4; ++r) {
      const int b = mbase + jm * 16 + r;
      const float cp = c_prev[(size_t)b * UNITS + u];
      const float zf = acc[jm][0][r] + bf_ + pfv * cp;
      const float zi = acc[jm][1][r] + bi_ + piv * cp;
      const float zc = acc[jm][2][r] + bc_;
      const float zo = acc[jm][3][r] + bo_;
      const float fg = 1.f / (1.f + __expf(-zf));
      const float ig = 1.f / (1.f + __expf(-zi));
      const float ct = 1.f - 2.f / (__expf(2.f * zc) + 1.f);   // tanh, NaN-safe
      const float cn = fg * cp + ig * ct;
      const float og = 1.f / (1.f + __expf(-(zo + pov * cn)));
      const float hn = og * (1.f - 2.f / (__expf(2.f * cn) + 1.f));
      out_h[(size_t)b * UNITS + u] = hn;
      out_c[(size_t)b * UNITS + u] = cn;
    }
  }
}

// ---------------------------------------------------------------------------
extern "C" void kernel_launch(void* const* d_in, const int* in_sizes, int n_in,
                              void* d_out, int out_size, void* d_ws, size_t ws_size,
                              hipStream_t stream) {
  const float* x      = (const float*)d_in[0];   // [8192,1024]
  const float* c_prev = (const float*)d_in[1];   // [8192,1024]
  const float* h_prev = (const float*)d_in[2];   // [8192,1024]
  const float* W      = (const float*)d_in[3];   // [1024,4096]
  const float* U      = (const float*)d_in[4];   // [1024,4096]
  const float* bias   = (const float*)d_in[5];   // [4096]
  const float* pf     = (const float*)d_in[6];   // [1024]
  const float* pi     = (const float*)d_in[7];
  const float* po     = (const float*)d_in[8];
  float* out_h = (float*)d_out;
  float* out_c = out_h + (size_t)BATCH * UNITS;

  u16* Abf = (u16*)d_ws;                           // 32 MB
  u16* Bbf = Abf + (size_t)BATCH * K2;             // 16 MB

  cast_fused_kernel<<<6144, 256, 0, stream>>>(x, h_prev, W, U, Abf, Bbf);
  lstm_gemm_kernel<<<(BATCH / BM) * (N4 / BN), 512, 0, stream>>>(
      Abf, Bbf, bias, c_prev, pf, pi, po, out_h, out_c);
}

// Round 8
// 165.893 us; speedup vs baseline: 5.9389x; 1.0275x over previous
//
#include <hip/hip_runtime.h>

typedef unsigned short u16;
typedef __attribute__((ext_vector_type(8))) short bf16x8;  // 8 bf16 in 4 VGPRs
typedef __attribute__((ext_vector_type(4))) float f32x4;

constexpr int BATCH = 8192;
constexpr int UNITS = 1024;
constexpr int K2    = 2048;   // combined K  ([x | h_prev])
constexpr int N4    = 4096;   // 4*UNITS gate columns
constexpr int BK    = 64;     // K-tile (keep: 128 B/row/tile fetch granularity)
constexpr int BM    = 256;    // batch rows per block
constexpr int BN    = 256;    // gate cols per block
constexpr int NKT   = K2 / BK;        // 32
constexpr int HSZ   = 256 * 32;       // u16 per half-buffer (256 rows x 32 k = 16 KB)

__device__ __forceinline__ u16 f2bf(float f) {
  unsigned u = __float_as_uint(f);
  u += 0x7fffu + ((u >> 16) & 1u);   // round-to-nearest-even
  return (u16)(u >> 16);
}

__device__ __forceinline__ void async_copy16(const void* g, void* l) {
  __builtin_amdgcn_global_load_lds(
      (const __attribute__((address_space(1))) void*)g,
      (__attribute__((address_space(3))) void*)l, 16, 0, 0);
}

// ---------------------------------------------------------------------------
// Fused cast kernel (unchanged — BW-bound near roofline, conflict-free).
// ---------------------------------------------------------------------------
__global__ __launch_bounds__(256) void cast_fused_kernel(
    const float* __restrict__ x, const float* __restrict__ h,
    const float* __restrict__ W, const float* __restrict__ U,
    u16* __restrict__ A, u16* __restrict__ B) {
  const int tid = threadIdx.x;
  if (blockIdx.x < 2048) {
    __shared__ float lds[64 * 69];
    const int bid = blockIdx.x;
    const int nb  = bid & 63;
    const int kb  = bid >> 6;
    const int n0  = nb * 64;
    const int k0  = kb * 64;
    const int jn  = n0 >> 10;
    const int q0  = (n0 & 1023) >> 4;
    const float* src = (k0 < UNITS) ? (W + (size_t)k0 * N4)
                                    : (U + (size_t)(k0 - UNITS) * N4);
    {
      const int kk  = tid >> 4;
      const int nn4 = (tid & 15) * 4;
#pragma unroll
      for (int r = 0; r < 4; ++r) {
        const int k = kk + r * 16;
        float4 v = *reinterpret_cast<const float4*>(&src[(size_t)k * N4 + n0 + nn4]);
        lds[k * 69 + nn4 + 0] = v.x;
        lds[k * 69 + nn4 + 1] = v.y;
        lds[k * 69 + nn4 + 2] = v.z;
        lds[k * 69 + nn4 + 3] = v.w;
      }
    }
    __syncthreads();
    {
      const int kk4 = (tid & 15) * 4;
#pragma unroll
      for (int pass = 0; pass < 4; ++pass) {
        const int rr  = (tid >> 4) + pass * 16;
        const int q   = q0 + (rr >> 4);
        const int low = rr & 15;
        const int p   = q * 64 + jn * 16 + low;
        union { ushort4 u4; u16 s[4]; } o;
#pragma unroll
        for (int j = 0; j < 4; ++j) o.s[j] = f2bf(lds[(kk4 + j) * 69 + rr]);
        *reinterpret_cast<ushort4*>(&B[(size_t)p * K2 + k0 + kk4]) = o.u4;
      }
    }
  } else {
    const int t0 = (blockIdx.x - 2048) * 256 + tid;
    const int stride = 4096 * 256;
#pragma unroll
    for (int s = 0; s < 4; ++s) {
      const int g = t0 + s * stride;
      const int idx = g * 4;
      const int b = idx >> 11;
      const int k = idx & 2047;
      const float* src = (k < UNITS) ? (x + (size_t)b * UNITS + k)
                                     : (h + (size_t)b * UNITS + (k - UNITS));
      float4 v = *reinterpret_cast<const float4*>(src);
      union { ushort4 u4; u16 sv[4]; } o;
      o.sv[0] = f2bf(v.x); o.sv[1] = f2bf(v.y);
      o.sv[2] = f2bf(v.z); o.sv[3] = f2bf(v.w);
      *reinterpret_cast<ushort4*>(A + idx) = o.u4;
    }
  }
}

// ---------------------------------------------------------------------------
// 256x256 GEMM + fused LSTM epilogue — deep-pipelined (T3+T4 faithful).
// 8 waves (2M x 4N), wave 128x64, acc[8][4].  LDS 128 KB:
//   A = [slot(2)][khalf(2)][256 rows][32 k], B likewise (8 x 16 KB halves).
// Per K-tile, 4 ks-major phases, each: {ds_read frag subtile (hoisted to
// phase top) | 2 stage-issues | [vmcnt(10) at p0/p2] | s_barrier |
// setprio(1) 16 MFMA setprio(0) | s_barrier}.
// Stage schedule (during kt): p0:A-h1(kt+1) p1:B-h1(kt+1) p2:A-h0(kt+2)
// p3:B-h0(kt+2) → prefetch depth 2 halves beyond dbuf; vmcnt(10) drains
// EXACTLY the half-pair the phase reads (traced kt0/kt1/steady); 14 loads
// in flight peak, NEVER drained to 0 in the loop (m218's counted-vmcnt
// lever — every prior round drained at each seam).
// Cross-wave visibility: every ds_read's data was guaranteed by a vmcnt
// >=2 barriers earlier.  Swizzle per half: slot = kgroup^(row&3), via
// pre-swizzled global source; stored[r][s]=s^(r&3), read slot q^(r&3) → q.
// ---------------------------------------------------------------------------
__global__ __launch_bounds__(512, 2) void lstm_gemm_kernel(
    const u16* __restrict__ A, const u16* __restrict__ B,
    const float* __restrict__ bias, const float* __restrict__ c_prev,
    const float* __restrict__ pf, const float* __restrict__ pi,
    const float* __restrict__ po,
    float* __restrict__ out_h, float* __restrict__ out_c) {
  __shared__ u16 lds[8 * HSZ];   // 131072 B
  u16* const Ab = lds;            // A halves: (slot*2 + h) * HSZ
  u16* const Bb = lds + 4 * HSZ;  // B halves: (slot*2 + h) * HSZ

  const int tid  = threadIdx.x;
  const int lane = tid & 63;
  const int wave = tid >> 6;
  const int quad = lane >> 4;
  const int c    = lane & 15;

  // XCD-aware bijective swizzle (nwg = 512): each XCD gets 64 consecutive
  // tiles = 4 A-panels (4 MB, L2-resident) x all 16 B-panels.
  int lin = blockIdx.y * 16 + blockIdx.x;
  lin = (lin & 7) * 64 + (lin >> 3);
  const int m0 = (lin >> 4) * BM;
  const int n0 = (lin & 15) * BN;

  const int wm = (wave >> 2) * 128;   // 2 M-wave-groups
  const int wn = (wave & 3) * 64;     // 4 N-wave-groups

  // ---- staging: round i covers rows i*128 + (tid>>2), 4 lanes/row,
  //      lane fetches k-group (t&3)^((t>>2)&3) of the target half --------
  const int swz4 = (tid & 3) ^ ((tid >> 2) & 3);
  const int rowS = tid >> 2;
  const u16* gA2 = A + (size_t)(m0 + rowS) * K2 + swz4 * 8;
  const u16* gB2 = B + (size_t)(n0 + rowS) * K2 + swz4 * 8;
  const int dst = tid * 8;   // u16: row tid>>2, slot tid&3 within half-buf

  // ---- fragment read offsets: row = base + c, slot = quad^(c&3) ---------
  const int slq  = (quad ^ (c & 3)) * 8;
  const int aoff = (wm + c) * 32 + slq;   // + jm*512 (16 rows)
  const int boff = (wn + c) * 32 + slq;   // + jn*512

  f32x4 acc[8][4] = {};

// stage round-pair for (matrix half-buffer base, tile t, half h)
#define STG2(gp, bb, t, h)                                                   \
  do {                                                                       \
    async_copy16((gp) + (size_t)(t) * 64 + (h) * 32, &(bb)[dst]);            \
    async_copy16((gp) + (size_t)128 * K2 + (size_t)(t) * 64 + (h) * 32,      \
                 &(bb)[4096 + dst]);                                         \
  } while (0)

  // ---- prologue: A-h0(0),B-h0(0),A-h1(0),B-h1(0),A-h0(1),B-h0(1) --------
  STG2(gA2, (Ab + 0 * HSZ), 0, 0);
  STG2(gB2, (Bb + 0 * HSZ), 0, 0);
  STG2(gA2, (Ab + 1 * HSZ), 0, 1);
  STG2(gB2, (Bb + 1 * HSZ), 0, 1);
  STG2(gA2, (Ab + 2 * HSZ), 1, 0);
  STG2(gB2, (Bb + 2 * HSZ), 1, 0);
  asm volatile("s_waitcnt vmcnt(8)" ::: "memory");   // tile0-h0 A,B landed
  __builtin_amdgcn_s_barrier();

#pragma unroll 2
  for (int kt = 0; kt < NKT; ++kt) {
    const int s  = kt & 1;
    const int s1 = s ^ 1;
    const u16* aH0 = Ab + (s * 2 + 0) * HSZ;
    const u16* aH1 = Ab + (s * 2 + 1) * HSZ;
    const u16* bH0 = Bb + (s * 2 + 0) * HSZ;
    const u16* bH1 = Bb + (s * 2 + 1) * HSZ;

    // ---- p0: read B-h0 + A-h0(jm0-3) | stage A-h1(kt+1) | vmcnt(10) ----
    bf16x8 b0[4], a0[4];
#pragma unroll
    for (int jn = 0; jn < 4; ++jn)
      b0[jn] = *(const bf16x8*)(bH0 + boff + jn * 512);
#pragma unroll
    for (int jm = 0; jm < 4; ++jm)
      a0[jm] = *(const bf16x8*)(aH0 + aoff + jm * 512);
    if (kt < NKT - 1) STG2(gA2, (Ab + (s1 * 2 + 1) * HSZ), kt + 1, 1);
    asm volatile("s_waitcnt vmcnt(10)" ::: "memory");
    __builtin_amdgcn_s_barrier();
    __builtin_amdgcn_s_setprio(1);
#pragma unroll
    for (int jm = 0; jm < 4; ++jm)
#pragma unroll
      for (int jn = 0; jn < 4; ++jn)
        acc[jm][jn] = __builtin_amdgcn_mfma_f32_16x16x32_bf16(
            a0[jm], b0[jn], acc[jm][jn], 0, 0, 0);
    __builtin_amdgcn_s_setprio(0);
    __builtin_amdgcn_s_barrier();

    // ---- p1: read A-h0(jm4-7) | stage B-h1(kt+1) -----------------------
    bf16x8 a1[4];
#pragma unroll
    for (int jm = 0; jm < 4; ++jm)
      a1[jm] = *(const bf16x8*)(aH0 + aoff + (4 + jm) * 512);
    if (kt < NKT - 1) STG2(gB2, (Bb + (s1 * 2 + 1) * HSZ), kt + 1, 1);
    __builtin_amdgcn_s_barrier();
    __builtin_amdgcn_s_setprio(1);
#pragma unroll
    for (int jm = 0; jm < 4; ++jm)
#pragma unroll
      for (int jn = 0; jn < 4; ++jn)
        acc[4 + jm][jn] = __builtin_amdgcn_mfma_f32_16x16x32_bf16(
            a1[jm], b0[jn], acc[4 + jm][jn], 0, 0, 0);
    __builtin_amdgcn_s_setprio(0);
    __builtin_amdgcn_s_barrier();

    // ---- p2: read B-h1 + A-h1(jm0-3) | stage A-h0(kt+2) | vmcnt(10) ----
    bf16x8 b1[4], a2[4];
#pragma unroll
    for (int jn = 0; jn < 4; ++jn)
      b1[jn] = *(const bf16x8*)(bH1 + boff + jn * 512);
#pragma unroll
    for (int jm = 0; jm < 4; ++jm)
      a2[jm] = *(const bf16x8*)(aH1 + aoff + jm * 512);
    if (kt < NKT - 2) STG2(gA2, (Ab + (s * 2 + 0) * HSZ), kt + 2, 0);
    asm volatile("s_waitcnt vmcnt(10)" ::: "memory");
    __builtin_amdgcn_s_barrier();
    __builtin_amdgcn_s_setprio(1);
#pragma unroll
    for (int jm = 0; jm < 4; ++jm)
#pragma unroll
      for (int jn = 0; jn < 4; ++jn)
        acc[jm][jn] = __builtin_amdgcn_mfma_f32_16x16x32_bf16(
            a2[jm], b1[jn], acc[jm][jn], 0, 0, 0);
    __builtin_amdgcn_s_setprio(0);
    __builtin_amdgcn_s_barrier();

    // ---- p3: read A-h1(jm4-7) | stage B-h0(kt+2) -----------------------
    bf16x8 a3[4];
#pragma unroll
    for (int jm = 0; jm < 4; ++jm)
      a3[jm] = *(const bf16x8*)(aH1 + aoff + (4 + jm) * 512);
    if (kt < NKT - 2) STG2(gB2, (Bb + (s * 2 + 0) * HSZ), kt + 2, 0);
    __builtin_amdgcn_s_barrier();
    __builtin_amdgcn_s_setprio(1);
#pragma unroll
    for (int jm = 0; jm < 4; ++jm)
#pragma unroll
      for (int jn = 0; jn < 4; ++jn)
        acc[4 + jm][jn] = __builtin_amdgcn_mfma_f32_16x16x32_bf16(
            a3[jm], b1[jn], acc[4 + jm][jn], 0, 0, 0);
    __builtin_amdgcn_s_setprio(0);
    if (kt < NKT - 1) __builtin_amdgcn_s_barrier();
  }
#undef STG2

  // ---- fused peephole-LSTM epilogue -------------------------------------
  const int u = ((n0 + wn) >> 2) + c;
  const float bf_ = bias[u];
  const float bi_ = bias[UNITS + u];
  const float bc_ = bias[2 * UNITS + u];
  const float bo_ = bias[3 * UNITS + u];
  const float pfv = pf[u], piv = pi[u], pov = po[u];
  const int mbase = m0 + wm + quad * 4;
#pragma unroll
  for (int jm = 0; jm < 8; ++jm) {
#pragma unroll
    for (int r = 0; r < 4; ++r) {
      const int b = mbase + jm * 16 + r;
      const float cp = c_prev[(size_t)b * UNITS + u];
      const float zf = acc[jm][0][r] + bf_ + pfv * cp;
      const float zi = acc[jm][1][r] + bi_ + piv * cp;
      const float zc = acc[jm][2][r] + bc_;
      const float zo = acc[jm][3][r] + bo_;
      const float fg = 1.f / (1.f + __expf(-zf));
      const float ig = 1.f / (1.f + __expf(-zi));
      const float ct = 1.f - 2.f / (__expf(2.f * zc) + 1.f);   // tanh, NaN-safe
      const float cn = fg * cp + ig * ct;
      const float og = 1.f / (1.f + __expf(-(zo + pov * cn)));
      const float hn = og * (1.f - 2.f / (__expf(2.f * cn) + 1.f));
      out_h[(size_t)b * UNITS + u] = hn;
      out_c[(size_t)b * UNITS + u] = cn;
    }
  }
}

// ---------------------------------------------------------------------------
extern "C" void kernel_launch(void* const* d_in, const int* in_sizes, int n_in,
                              void* d_out, int out_size, void* d_ws, size_t ws_size,
                              hipStream_t stream) {
  const float* x      = (const float*)d_in[0];   // [8192,1024]
  const float* c_prev = (const float*)d_in[1];   // [8192,1024]
  const float* h_prev = (const float*)d_in[2];   // [8192,1024]
  const float* W      = (const float*)d_in[3];   // [1024,4096]
  const float* U      = (const float*)d_in[4];   // [1024,4096]
  const float* bias   = (const float*)d_in[5];   // [4096]
  const float* pf     = (const float*)d_in[6];   // [1024]
  const float* pi     = (const float*)d_in[7];
  const float* po     = (const float*)d_in[8];
  float* out_h = (float*)d_out;
  float* out_c = out_h + (size_t)BATCH * UNITS;

  u16* Abf = (u16*)d_ws;                           // 32 MB
  u16* Bbf = Abf + (size_t)BATCH * K2;             // 16 MB

  cast_fused_kernel<<<6144, 256, 0, stream>>>(x, h_prev, W, U, Abf, Bbf);
  lstm_gemm_kernel<<<dim3(N4 / BN, BATCH / BM), 512, 0, stream>>>(
      Abf, Bbf, bias, c_prev, pf, pi, po, out_h, out_c);
}